// Round 10
// baseline (500.053 us; speedup 1.0000x reference)
//
#include <hip/hip_runtime.h>
#include <cfloat>
#include <cstdint>

#define N_NODES 50000
#define N_EDGES 600000
#define HDIM    128
#define NGRAPH  2000
#define BN_EPS  1e-5f

typedef float f4 __attribute__((ext_vector_type(4)));

// ---------------- CSR build ----------------

__global__ void k_init(int* degi, int* seg_s, int* seg_e) {
    int i = blockIdx.x * 256 + threadIdx.x;
    if (i < N_NODES) degi[i] = 1;                  // self-loop
    if (i < NGRAPH) { seg_s[i] = 0x7FFFFFFF; seg_e[i] = 0; }
}

__global__ void k_count_seg(const int* __restrict__ ei, int* degi,
                            const int* __restrict__ batch, int* seg_s, int* seg_e) {
    int e = blockIdx.x * 256 + threadIdx.x;
    if (e < N_EDGES) atomicAdd(&degi[ei[N_EDGES + e]], 1);
    if (e < N_NODES) {
        int g = batch[e];
        atomicMin(&seg_s[g], e);
        atomicMax(&seg_e[g], e + 1);
    }
}

__global__ void k_scanA(const int* __restrict__ degi, int* ptr, int* bsum, float* dinv) {
    __shared__ int t[256];
    int i = blockIdx.x * 256 + threadIdx.x;
    int v = (i < N_NODES) ? degi[i] : 0;
    if (i < N_NODES) dinv[i] = rsqrtf((float)v);
    t[threadIdx.x] = v; __syncthreads();
    for (int off = 1; off < 256; off <<= 1) {
        int a = (threadIdx.x >= off) ? t[threadIdx.x - off] : 0;
        __syncthreads();
        t[threadIdx.x] += a;
        __syncthreads();
    }
    if (i < N_NODES) ptr[i + 1] = t[threadIdx.x];
    if (threadIdx.x == 255) bsum[blockIdx.x] = t[255];
}

__global__ void k_scanB(const int* __restrict__ bsum, int* boff, int nb) {
    __shared__ int t[256];
    int i = threadIdx.x;
    int v = (i < nb) ? bsum[i] : 0;
    t[i] = v; __syncthreads();
    for (int off = 1; off < 256; off <<= 1) {
        int a = (i >= off) ? t[i - off] : 0;
        __syncthreads();
        t[i] += a;
        __syncthreads();
    }
    if (i < nb) boff[i] = t[i] - v;
}

__global__ void k_scanC(int* ptr, const int* __restrict__ boff, int* cursor) {
    int i = blockIdx.x * 256 + threadIdx.x;
    if (i < N_NODES) {
        int val = ptr[i + 1] + boff[blockIdx.x];
        ptr[i + 1] = val;
        if (i + 1 < N_NODES) cursor[i + 1] = val;
    }
    if (i == 0) { ptr[0] = 0; cursor[0] = 0; }
}

__global__ void k_fill(const int* __restrict__ ei, const float* __restrict__ dinv,
                       int* cursor, int2* meta) {
    int e = blockIdx.x * 256 + threadIdx.x;
    if (e < N_EDGES) {
        int r = ei[e], c = ei[N_EDGES + e];
        int pos = atomicAdd(&cursor[c], 1);
        meta[pos] = make_int2(r, __float_as_int(dinv[r] * dinv[c]));
    } else if (e < N_EDGES + N_NODES) {
        int v = e - N_EDGES;
        int pos = atomicAdd(&cursor[v], 1);
        float d = dinv[v];
        meta[pos] = make_int2(v, __float_as_int(d * d));
    }
}

// ---------------- fused GCN layer at 8-node granularity ----------------
// out = relu(BN( (S·h)·W + b )) via associativity.
// Phase 1 = EXACTLY the proven 46.6us aggregate shape: 6250 blocks, 8 nodes/
// block, 32 thr/node, f4/thread, edge unroll x8, PLAIN loads (L2 reuse).
// Phase 2 = tiny GEMM of the 8 aggregated rows vs W (LDS broadcast reads,
// W streamed through L1/L2) + fused bias+BN+ReLU.
// Overlap happens ACROSS blocks: ~24 resident blocks/CU at staggered phases
// keep both the memory pipe (gatherers) and VALU pipe (GEMMers) busy.

__global__ __launch_bounds__(256) void k_layer(const f4* __restrict__ h4,
                                               const int* __restrict__ ptr,
                                               const int2* __restrict__ meta,
                                               const f4* __restrict__ W4,
                                               const f4* __restrict__ bias4,
                                               const f4* __restrict__ bng4,
                                               const f4* __restrict__ bnb4,
                                               const f4* __restrict__ bnm4,
                                               const f4* __restrict__ bnv4,
                                               f4* __restrict__ hout4) {
    __shared__ f4 rows[8 * 32];          // 4 KB: 8 aggregated rows
    int ng = threadIdx.x >> 5;           // node slot 0..7
    int c  = threadIdx.x & 31;           // f4 channel slot 0..31
    int v  = blockIdx.x * 8 + ng;        // 6250*8 == 50000: always in range

    // ---- Phase 1: gather S·h row for node v ----
    {
        int e0 = ptr[v], e1 = ptr[v + 1];
        float ax = 0.f, ay = 0.f, az = 0.f, aw = 0.f;
        int j = e0;
        for (; j + 8 <= e1; j += 8) {
            int2 m[8];
#pragma unroll
            for (int i = 0; i < 8; i++) m[i] = meta[j + i];
            f4 vv[8];
#pragma unroll
            for (int i = 0; i < 8; i++) vv[i] = h4[(size_t)m[i].x * 32 + c];
#pragma unroll
            for (int i = 0; i < 8; i++) {
                float n = __int_as_float(m[i].y);
                ax += n * vv[i].x; ay += n * vv[i].y;
                az += n * vv[i].z; aw += n * vv[i].w;
            }
        }
        int rem = e1 - j;                // 0..7 masked tail
        if (rem) {
            int2 m[8];
#pragma unroll
            for (int i = 0; i < 8; i++) m[i] = meta[j + (i < rem ? i : 0)];
            f4 vv[8];
#pragma unroll
            for (int i = 0; i < 8; i++) vv[i] = h4[(size_t)m[i].x * 32 + c];
#pragma unroll
            for (int i = 0; i < 8; i++) {
                float n = (i < rem) ? __int_as_float(m[i].y) : 0.f;
                ax += n * vv[i].x; ay += n * vv[i].y;
                az += n * vv[i].z; aw += n * vv[i].w;
            }
        }
        f4 a; a.x = ax; a.y = ay; a.z = az; a.w = aw;
        rows[ng * 32 + c] = a;
    }
    __syncthreads();

    // ---- Phase 2: row(1x128) @ W(128x128) for this thread's 4 channels ----
    const f4* row = &rows[ng * 32];      // half-wave broadcast reads
    f4 acc = {0.f, 0.f, 0.f, 0.f};
#pragma unroll 4
    for (int kc = 0; kc < 32; kc++) {
        f4 hv = row[kc];
        f4 w0 = W4[(kc * 4 + 0) * 32 + c];
        f4 w1 = W4[(kc * 4 + 1) * 32 + c];
        f4 w2 = W4[(kc * 4 + 2) * 32 + c];
        f4 w3 = W4[(kc * 4 + 3) * 32 + c];
        acc += hv.x * w0 + hv.y * w1 + hv.z * w2 + hv.w * w3;
    }

    // ---- fused epilogue: + bias, BN (eval), ReLU ----
    f4 bs = bias4[c], g = bng4[c], bb = bnb4[c], m = bnm4[c], vv = bnv4[c];
    f4 sc, tr;
    sc.x = g.x * rsqrtf(vv.x + BN_EPS); tr.x = bb.x - m.x * sc.x;
    sc.y = g.y * rsqrtf(vv.y + BN_EPS); tr.y = bb.y - m.y * sc.y;
    sc.z = g.z * rsqrtf(vv.z + BN_EPS); tr.z = bb.z - m.z * sc.z;
    sc.w = g.w * rsqrtf(vv.w + BN_EPS); tr.w = bb.w - m.w * sc.w;
    f4 a = (acc + bs) * sc + tr;
    f4 r;
    r.x = fmaxf(a.x, 0.f); r.y = fmaxf(a.y, 0.f);
    r.z = fmaxf(a.z, 0.f); r.w = fmaxf(a.w, 0.f);
    hout4[(size_t)v * 32 + c] = r;
}

// ---------------- fused pool (mean|max|sum) + MLP ----------------
// 125 blocks x 512 threads, 16 graphs/block; l1W loads reused across 4
// graphs in registers. Plain loads (no nt).

__global__ __launch_bounds__(512) void k_pool(const float* __restrict__ h,
                                              const int* __restrict__ seg_s,
                                              const int* __restrict__ seg_e,
                                              const float* __restrict__ l1W,
                                              const float* __restrict__ l1b,
                                              const float* __restrict__ l2W,
                                              const float* __restrict__ l2b,
                                              float* __restrict__ out) {
    __shared__ float z[16][3 * HDIM];   // 24 KB
    __shared__ float red[16][2];
    int sub = threadIdx.x >> 7;          // 0..3
    int c   = threadIdx.x & 127;

#pragma unroll
    for (int pass = 0; pass < 4; pass++) {
        int lg = pass * 4 + sub;
        int g  = blockIdx.x * 16 + lg;
        int s = seg_s[g], e = seg_e[g];
        float sum = 0.f, mx = -FLT_MAX;
        for (int i = s; i < e; i++) {
            float val = h[(size_t)i * HDIM + c];
            sum += val;
            mx = fmaxf(mx, val);
        }
        int cnt = (s < e) ? (e - s) : 0;
        if (cnt == 0) { mx = 0.f; sum = 0.f; }
        z[lg][c] = sum / (float)(cnt > 1 ? cnt : 1);
        z[lg][HDIM + c] = mx;
        z[lg][2 * HDIM + c] = sum;
    }
    __syncthreads();

    float o[4];
#pragma unroll
    for (int q = 0; q < 4; q++) o[q] = l1b[c];
    for (int k4 = 0; k4 < 96; k4++) {
        float w0 = l1W[(k4 * 4 + 0) * HDIM + c];
        float w1 = l1W[(k4 * 4 + 1) * HDIM + c];
        float w2 = l1W[(k4 * 4 + 2) * HDIM + c];
        float w3 = l1W[(k4 * 4 + 3) * HDIM + c];
#pragma unroll
        for (int q = 0; q < 4; q++) {
            const float4 zz = *(const float4*)&z[sub * 4 + q][k4 * 4];
            o[q] += zz.x * w0 + zz.y * w1 + zz.z * w2 + zz.w * w3;
        }
    }
    float l2 = l2W[c];
#pragma unroll
    for (int q = 0; q < 4; q++) {
        float p = fmaxf(o[q], 0.f) * l2;
#pragma unroll
        for (int off = 32; off; off >>= 1) p += __shfl_down(p, off, 64);
        if ((threadIdx.x & 63) == 0) red[sub * 4 + q][c >> 6] = p;
    }
    __syncthreads();
    if (threadIdx.x < 16)
        out[blockIdx.x * 16 + threadIdx.x] = red[threadIdx.x][0] + red[threadIdx.x][1] + l2b[0];
}

// ---------------- launch ----------------

extern "C" void kernel_launch(void* const* d_in, const int* in_sizes, int n_in,
                              void* d_out, int out_size, void* d_ws, size_t ws_size,
                              hipStream_t stream) {
    const float* x   = (const float*)d_in[0];
    const int*   ei  = (const int*)d_in[1];
    const int*   bat = (const int*)d_in[2];
    const float* W1  = (const float*)d_in[3];
    const float* b1  = (const float*)d_in[4];
    const float* W2  = (const float*)d_in[5];
    const float* b2  = (const float*)d_in[6];
    const float* W3  = (const float*)d_in[7];
    const float* b3  = (const float*)d_in[8];
    const float* bng = (const float*)d_in[9];
    const float* bnb = (const float*)d_in[10];
    const float* bnm = (const float*)d_in[11];
    const float* bnv = (const float*)d_in[12];
    const float* l1W = (const float*)d_in[13];
    const float* l1b = (const float*)d_in[14];
    const float* l2W = (const float*)d_in[15];
    const float* l2b = (const float*)d_in[16];
    float* out = (float*)d_out;

    char* ws = (char*)d_ws;
    size_t off = 0;
    auto alloc = [&](size_t bytes) -> char* {
        char* p = ws + off;
        off = (off + bytes + 255) & ~(size_t)255;
        return p;
    };
    int*   degi   = (int*)alloc((size_t)N_NODES * 4);
    float* dinv   = (float*)alloc((size_t)N_NODES * 4);
    int*   ptr    = (int*)alloc((size_t)(N_NODES + 1) * 4);
    int*   cursor = (int*)alloc((size_t)N_NODES * 4);
    int*   bsum   = (int*)alloc(256 * 4);
    int*   boff   = (int*)alloc(256 * 4);
    int*   seg_s  = (int*)alloc((size_t)NGRAPH * 4);
    int*   seg_e  = (int*)alloc((size_t)NGRAPH * 4);
    int2*  meta   = (int2*)alloc((size_t)(N_EDGES + N_NODES) * 8);
    float* hA     = (float*)alloc((size_t)N_NODES * HDIM * 4);
    float* hB     = (float*)alloc((size_t)N_NODES * HDIM * 4);
    (void)ws_size;

    int nblk = (N_NODES + 255) / 256;  // 196

    k_init<<<nblk, 256, 0, stream>>>(degi, seg_s, seg_e);
    k_count_seg<<<(N_EDGES + 255) / 256, 256, 0, stream>>>(ei, degi, bat, seg_s, seg_e);
    k_scanA<<<nblk, 256, 0, stream>>>(degi, ptr, bsum, dinv);
    k_scanB<<<1, 256, 0, stream>>>(bsum, boff, nblk);
    k_scanC<<<nblk, 256, 0, stream>>>(ptr, boff, cursor);
    k_fill<<<(N_EDGES + N_NODES + 255) / 256, 256, 0, stream>>>(ei, dinv, cursor, meta);

    int lb = N_NODES / 8;  // 6250 exact

    // layer 1: x -> hA
    k_layer<<<lb, 256, 0, stream>>>((const f4*)x, ptr, meta, (const f4*)W1,
                                    (const f4*)b1,
                                    (const f4*)(bng + 0), (const f4*)(bnb + 0),
                                    (const f4*)(bnm + 0), (const f4*)(bnv + 0),
                                    (f4*)hA);
    // layer 2: hA -> hB
    k_layer<<<lb, 256, 0, stream>>>((const f4*)hA, ptr, meta, (const f4*)W2,
                                    (const f4*)b2,
                                    (const f4*)(bng + HDIM), (const f4*)(bnb + HDIM),
                                    (const f4*)(bnm + HDIM), (const f4*)(bnv + HDIM),
                                    (f4*)hB);
    // layer 3: hB -> hA
    k_layer<<<lb, 256, 0, stream>>>((const f4*)hB, ptr, meta, (const f4*)W3,
                                    (const f4*)b3,
                                    (const f4*)(bng + 2 * HDIM), (const f4*)(bnb + 2 * HDIM),
                                    (const f4*)(bnm + 2 * HDIM), (const f4*)(bnv + 2 * HDIM),
                                    (f4*)hA);

    k_pool<<<NGRAPH / 16, 512, 0, stream>>>(hA, seg_s, seg_e, l1W, l1b, l2W, l2b, out);
}

// Round 11
// 378.936 us; speedup vs baseline: 1.3196x; 1.3196x over previous
//
#include <hip/hip_runtime.h>
#include <cfloat>
#include <cstdint>

#define N_NODES 50000
#define N_EDGES 600000
#define HDIM    128
#define NGRAPH  2000
#define BN_EPS  1e-5f

typedef float f4 __attribute__((ext_vector_type(4)));

// ---------------- CSR build ----------------

__global__ void k_init(int* degi, int* seg_s, int* seg_e) {
    int i = blockIdx.x * 256 + threadIdx.x;
    if (i < N_NODES) degi[i] = 1;                  // self-loop
    if (i < NGRAPH) { seg_s[i] = 0x7FFFFFFF; seg_e[i] = 0; }
}

__global__ void k_count_seg(const int* __restrict__ ei, int* degi,
                            const int* __restrict__ batch, int* seg_s, int* seg_e) {
    int e = blockIdx.x * 256 + threadIdx.x;
    if (e < N_EDGES) atomicAdd(&degi[ei[N_EDGES + e]], 1);
    if (e < N_NODES) {
        int g = batch[e];
        atomicMin(&seg_s[g], e);
        atomicMax(&seg_e[g], e + 1);
    }
}

__global__ void k_scanA(const int* __restrict__ degi, int* ptr, int* bsum, float* dinv) {
    __shared__ int t[256];
    int i = blockIdx.x * 256 + threadIdx.x;
    int v = (i < N_NODES) ? degi[i] : 0;
    if (i < N_NODES) dinv[i] = rsqrtf((float)v);
    t[threadIdx.x] = v; __syncthreads();
    for (int off = 1; off < 256; off <<= 1) {
        int a = (threadIdx.x >= off) ? t[threadIdx.x - off] : 0;
        __syncthreads();
        t[threadIdx.x] += a;
        __syncthreads();
    }
    if (i < N_NODES) ptr[i + 1] = t[threadIdx.x];
    if (threadIdx.x == 255) bsum[blockIdx.x] = t[255];
}

__global__ void k_scanB(const int* __restrict__ bsum, int* boff, int nb) {
    __shared__ int t[256];
    int i = threadIdx.x;
    int v = (i < nb) ? bsum[i] : 0;
    t[i] = v; __syncthreads();
    for (int off = 1; off < 256; off <<= 1) {
        int a = (i >= off) ? t[i - off] : 0;
        __syncthreads();
        t[i] += a;
        __syncthreads();
    }
    if (i < nb) boff[i] = t[i] - v;
}

__global__ void k_scanC(int* ptr, const int* __restrict__ boff, int* cursor) {
    int i = blockIdx.x * 256 + threadIdx.x;
    if (i < N_NODES) {
        int val = ptr[i + 1] + boff[blockIdx.x];
        ptr[i + 1] = val;
        if (i + 1 < N_NODES) cursor[i + 1] = val;
    }
    if (i == 0) { ptr[0] = 0; cursor[0] = 0; }
}

__global__ void k_fill(const int* __restrict__ ei, const float* __restrict__ dinv,
                       int* cursor, int2* meta) {
    int e = blockIdx.x * 256 + threadIdx.x;
    if (e < N_EDGES) {
        int r = ei[e], c = ei[N_EDGES + e];
        int pos = atomicAdd(&cursor[c], 1);
        meta[pos] = make_int2(r, __float_as_int(dinv[r] * dinv[c]));
    } else if (e < N_EDGES + N_NODES) {
        int v = e - N_EDGES;
        int pos = atomicAdd(&cursor[v], 1);
        float d = dinv[v];
        meta[pos] = make_int2(v, __float_as_int(d * d));
    }
}

// ---------------- dense transform: hout = hin @ W ----------------
// 128-node tile, 512 threads: h-tile (64 KB) in LDS; W streamed from global
// but amortized over 128 nodes (25 MB total W traffic vs 100 MB at 32-node).
// Thread = 8 nodes x 4 channels = 8 f4 accumulators. Half-wave broadcast
// LDS reads (conflict-free).

__global__ __launch_bounds__(512) void k_transform(const f4* __restrict__ hin4,
                                                   const f4* __restrict__ W4,
                                                   f4* __restrict__ hout4) {
    __shared__ f4 Hs[128 * 32];   // 64 KB
    size_t g4 = (size_t)blockIdx.x * 4096;
#pragma unroll
    for (int p = 0; p < 8; p++) {
        int idx = threadIdx.x + p * 512;
        f4 val = {0.f, 0.f, 0.f, 0.f};
        if (g4 + idx < (size_t)N_NODES * 32) val = hin4[g4 + idx];
        Hs[idx] = val;
    }
    __syncthreads();

    int ct = threadIdx.x & 31;       // channel group: channels 4ct..4ct+3
    int ng = threadIdx.x >> 5;       // node group 0..15: local nodes 8ng..8ng+7
    int n0 = blockIdx.x * 128 + ng * 8;

    f4 acc[8];
#pragma unroll
    for (int i = 0; i < 8; i++) acc[i] = (f4){0.f, 0.f, 0.f, 0.f};

#pragma unroll 2
    for (int kc = 0; kc < 32; kc++) {
        f4 w0 = W4[(kc * 4 + 0) * 32 + ct];
        f4 w1 = W4[(kc * 4 + 1) * 32 + ct];
        f4 w2 = W4[(kc * 4 + 2) * 32 + ct];
        f4 w3 = W4[(kc * 4 + 3) * 32 + ct];
#pragma unroll
        for (int i = 0; i < 8; i++) {
            f4 h = Hs[(ng * 8 + i) * 32 + kc];
            acc[i] += h.x * w0 + h.y * w1 + h.z * w2 + h.w * w3;
        }
    }

#pragma unroll
    for (int i = 0; i < 8; i++) {
        int nidx = n0 + i;
        if (nidx < N_NODES) hout4[(size_t)nidx * 32 + ct] = acc[i];
    }
}

// ---------------- aggregate + bias + BN + ReLU ----------------
// Proven 46.6us shape: 6250 blocks, 8 nodes/block, 32 thr/node, f4/thread,
// edge unroll x8, PLAIN loads (L2 reuse matters: nt cost +25us in R9).

__global__ __launch_bounds__(256) void k_aggregate(const f4* __restrict__ h4,
                                                   const int* __restrict__ ptr,
                                                   const int2* __restrict__ meta,
                                                   const f4* __restrict__ bias4,
                                                   const f4* __restrict__ bng4,
                                                   const f4* __restrict__ bnb4,
                                                   const f4* __restrict__ bnm4,
                                                   const f4* __restrict__ bnv4,
                                                   f4* __restrict__ hout4) {
    int v = blockIdx.x * 8 + (threadIdx.x >> 5);
    int c = threadIdx.x & 31;
    if (v >= N_NODES) return;
    int e0 = ptr[v], e1 = ptr[v + 1];

    float ax = 0.f, ay = 0.f, az = 0.f, aw = 0.f;
    int j = e0;
    for (; j + 8 <= e1; j += 8) {
        int2 m[8];
#pragma unroll
        for (int i = 0; i < 8; i++) m[i] = meta[j + i];
        f4 vv[8];
#pragma unroll
        for (int i = 0; i < 8; i++) vv[i] = h4[(size_t)m[i].x * 32 + c];
#pragma unroll
        for (int i = 0; i < 8; i++) {
            float n = __int_as_float(m[i].y);
            ax += n * vv[i].x; ay += n * vv[i].y;
            az += n * vv[i].z; aw += n * vv[i].w;
        }
    }
    int rem = e1 - j;
    if (rem) {
        int2 m[8];
#pragma unroll
        for (int i = 0; i < 8; i++) m[i] = meta[j + (i < rem ? i : 0)];
        f4 vv[8];
#pragma unroll
        for (int i = 0; i < 8; i++) vv[i] = h4[(size_t)m[i].x * 32 + c];
#pragma unroll
        for (int i = 0; i < 8; i++) {
            float n = (i < rem) ? __int_as_float(m[i].y) : 0.f;
            ax += n * vv[i].x; ay += n * vv[i].y;
            az += n * vv[i].z; aw += n * vv[i].w;
        }
    }

    f4 bs = bias4[c], g = bng4[c], bb = bnb4[c], m = bnm4[c], vv = bnv4[c];
    float sx = g.x * rsqrtf(vv.x + BN_EPS), tx = bb.x - m.x * sx;
    float sy = g.y * rsqrtf(vv.y + BN_EPS), ty = bb.y - m.y * sy;
    float sz = g.z * rsqrtf(vv.z + BN_EPS), tz = bb.z - m.z * sz;
    float sw = g.w * rsqrtf(vv.w + BN_EPS), tw = bb.w - m.w * sw;
    f4 r;
    r.x = fmaxf((ax + bs.x) * sx + tx, 0.f);
    r.y = fmaxf((ay + bs.y) * sy + ty, 0.f);
    r.z = fmaxf((az + bs.z) * sz + tz, 0.f);
    r.w = fmaxf((aw + bs.w) * sw + tw, 0.f);
    hout4[(size_t)v * 32 + c] = r;
}

// ---------------- fused pool (mean|max|sum) + MLP ----------------
// 125 blocks x 512 threads, 16 graphs/block; l1W loads reused across 4
// graphs in registers (l1W L2 traffic 98 MB -> 24.5 MB). Plain loads.

__global__ __launch_bounds__(512) void k_pool(const float* __restrict__ h,
                                              const int* __restrict__ seg_s,
                                              const int* __restrict__ seg_e,
                                              const float* __restrict__ l1W,
                                              const float* __restrict__ l1b,
                                              const float* __restrict__ l2W,
                                              const float* __restrict__ l2b,
                                              float* __restrict__ out) {
    __shared__ float z[16][3 * HDIM];   // 24 KB
    __shared__ float red[16][2];
    int sub = threadIdx.x >> 7;          // 0..3
    int c   = threadIdx.x & 127;

#pragma unroll
    for (int pass = 0; pass < 4; pass++) {
        int lg = pass * 4 + sub;
        int g  = blockIdx.x * 16 + lg;
        int s = seg_s[g], e = seg_e[g];
        float sum = 0.f, mx = -FLT_MAX;
        for (int i = s; i < e; i++) {
            float val = h[(size_t)i * HDIM + c];
            sum += val;
            mx = fmaxf(mx, val);
        }
        int cnt = (s < e) ? (e - s) : 0;
        if (cnt == 0) { mx = 0.f; sum = 0.f; }
        z[lg][c] = sum / (float)(cnt > 1 ? cnt : 1);
        z[lg][HDIM + c] = mx;
        z[lg][2 * HDIM + c] = sum;
    }
    __syncthreads();

    float o[4];
#pragma unroll
    for (int q = 0; q < 4; q++) o[q] = l1b[c];
    for (int k4 = 0; k4 < 96; k4++) {
        float w0 = l1W[(k4 * 4 + 0) * HDIM + c];
        float w1 = l1W[(k4 * 4 + 1) * HDIM + c];
        float w2 = l1W[(k4 * 4 + 2) * HDIM + c];
        float w3 = l1W[(k4 * 4 + 3) * HDIM + c];
#pragma unroll
        for (int q = 0; q < 4; q++) {
            const float4 zz = *(const float4*)&z[sub * 4 + q][k4 * 4];
            o[q] += zz.x * w0 + zz.y * w1 + zz.z * w2 + zz.w * w3;
        }
    }
    float l2 = l2W[c];
#pragma unroll
    for (int q = 0; q < 4; q++) {
        float p = fmaxf(o[q], 0.f) * l2;
#pragma unroll
        for (int off = 32; off; off >>= 1) p += __shfl_down(p, off, 64);
        if ((threadIdx.x & 63) == 0) red[sub * 4 + q][c >> 6] = p;
    }
    __syncthreads();
    if (threadIdx.x < 16)
        out[blockIdx.x * 16 + threadIdx.x] = red[threadIdx.x][0] + red[threadIdx.x][1] + l2b[0];
}

// ---------------- launch ----------------

extern "C" void kernel_launch(void* const* d_in, const int* in_sizes, int n_in,
                              void* d_out, int out_size, void* d_ws, size_t ws_size,
                              hipStream_t stream) {
    const float* x   = (const float*)d_in[0];
    const int*   ei  = (const int*)d_in[1];
    const int*   bat = (const int*)d_in[2];
    const float* W1  = (const float*)d_in[3];
    const float* b1  = (const float*)d_in[4];
    const float* W2  = (const float*)d_in[5];
    const float* b2  = (const float*)d_in[6];
    const float* W3  = (const float*)d_in[7];
    const float* b3  = (const float*)d_in[8];
    const float* bng = (const float*)d_in[9];
    const float* bnb = (const float*)d_in[10];
    const float* bnm = (const float*)d_in[11];
    const float* bnv = (const float*)d_in[12];
    const float* l1W = (const float*)d_in[13];
    const float* l1b = (const float*)d_in[14];
    const float* l2W = (const float*)d_in[15];
    const float* l2b = (const float*)d_in[16];
    float* out = (float*)d_out;

    char* ws = (char*)d_ws;
    size_t off = 0;
    auto alloc = [&](size_t bytes) -> char* {
        char* p = ws + off;
        off = (off + bytes + 255) & ~(size_t)255;
        return p;
    };
    int*   degi   = (int*)alloc((size_t)N_NODES * 4);
    float* dinv   = (float*)alloc((size_t)N_NODES * 4);
    int*   ptr    = (int*)alloc((size_t)(N_NODES + 1) * 4);
    int*   cursor = (int*)alloc((size_t)N_NODES * 4);
    int*   bsum   = (int*)alloc(256 * 4);
    int*   boff   = (int*)alloc(256 * 4);
    int*   seg_s  = (int*)alloc((size_t)NGRAPH * 4);
    int*   seg_e  = (int*)alloc((size_t)NGRAPH * 4);
    int2*  meta   = (int2*)alloc((size_t)(N_EDGES + N_NODES) * 8);
    float* hA     = (float*)alloc((size_t)N_NODES * HDIM * 4);
    float* hB     = (float*)alloc((size_t)N_NODES * HDIM * 4);
    (void)ws_size;

    int nblk = (N_NODES + 255) / 256;  // 196

    k_init<<<nblk, 256, 0, stream>>>(degi, seg_s, seg_e);
    k_count_seg<<<(N_EDGES + 255) / 256, 256, 0, stream>>>(ei, degi, bat, seg_s, seg_e);
    k_scanA<<<nblk, 256, 0, stream>>>(degi, ptr, bsum, dinv);
    k_scanB<<<1, 256, 0, stream>>>(bsum, boff, nblk);
    k_scanC<<<nblk, 256, 0, stream>>>(ptr, boff, cursor);
    k_fill<<<(N_EDGES + N_NODES + 255) / 256, 256, 0, stream>>>(ei, dinv, cursor, meta);

    int tb = (N_NODES + 127) / 128;  // 391
    int ab = (N_NODES + 7) / 8;      // 6250

    // layer 1
    k_transform<<<tb, 512, 0, stream>>>((const f4*)x, (const f4*)W1, (f4*)hA);
    k_aggregate<<<ab, 256, 0, stream>>>((const f4*)hA, ptr, meta, (const f4*)b1,
                                        (const f4*)(bng + 0), (const f4*)(bnb + 0),
                                        (const f4*)(bnm + 0), (const f4*)(bnv + 0),
                                        (f4*)hB);
    // layer 2
    k_transform<<<tb, 512, 0, stream>>>((const f4*)hB, (const f4*)W2, (f4*)hA);
    k_aggregate<<<ab, 256, 0, stream>>>((const f4*)hA, ptr, meta, (const f4*)b2,
                                        (const f4*)(bng + HDIM), (const f4*)(bnb + HDIM),
                                        (const f4*)(bnm + HDIM), (const f4*)(bnv + HDIM),
                                        (f4*)hB);
    // layer 3
    k_transform<<<tb, 512, 0, stream>>>((const f4*)hB, (const f4*)W3, (f4*)hA);
    k_aggregate<<<ab, 256, 0, stream>>>((const f4*)hA, ptr, meta, (const f4*)b3,
                                        (const f4*)(bng + 2 * HDIM), (const f4*)(bnb + 2 * HDIM),
                                        (const f4*)(bnm + 2 * HDIM), (const f4*)(bnv + 2 * HDIM),
                                        (f4*)hB);

    k_pool<<<NGRAPH / 16, 512, 0, stream>>>(hB, seg_s, seg_e, l1W, l1b, l2W, l2b, out);
}